// Round 12
// baseline (266.571 us; speedup 1.0000x reference)
//
#include <hip/hip_runtime.h>
#include <hip/hip_bf16.h>

#define N_NODES 100000
#define N_EDGES 1600000
#define N_GRAPHS 128
#define IN_F 128
#define H_F 128
#define OUT_F 64
#define HID 10
#define NCLS 10
#define XPAD 136    // LDS row stride in bf16 (pad 128 -> 136: 16-way conflict -> free 2-way)
#define BSH 7                     // bucket = node >> 7 (128-node windows)
#define NBUCK 782                 // ceil(100000/128)
#define SBLK 128                  // edge partitions for hist/scatter
#define EPB (N_EDGES / SBLK)      // 12500, exact
#define NB_PREP 4

typedef __attribute__((ext_vector_type(8))) short bf16x8;
typedef __attribute__((ext_vector_type(4))) float f32x4;
typedef __attribute__((ext_vector_type(2))) float f32x2;

__device__ __forceinline__ float bl(unsigned int u) { return __uint_as_float(u << 16); }
__device__ __forceinline__ float bh(unsigned int u) { return __uint_as_float(u & 0xffff0000u); }

// ---------------- phase 1: LDS-privatized bucket histograms (dst & src) + weight prep + part zero ----------------
__global__ __launch_bounds__(1024) void k_hist2(const int* __restrict__ src, const int* __restrict__ dst,
                                                int* __restrict__ Pd, int* __restrict__ Ps,
                                                const float* __restrict__ W1, const float* __restrict__ W2,
                                                unsigned short* __restrict__ Wt1, unsigned short* __restrict__ Wt2,
                                                float* __restrict__ part) {
    __shared__ int hd[NBUCK];
    __shared__ int hs[NBUCK];
    const int blk = blockIdx.x;
    if (blk < SBLK) {
        for (int i = threadIdx.x; i < NBUCK; i += 1024) { hd[i] = 0; hs[i] = 0; }
        __syncthreads();
        const int base = blk * EPB;
        for (int i = threadIdx.x; i < EPB; i += 1024) {
            atomicAdd(&hd[dst[base + i] >> BSH], 1);
            atomicAdd(&hs[src[base + i] >> BSH], 1);
        }
        __syncthreads();
        for (int b = threadIdx.x; b < NBUCK; b += 1024) {
            Pd[b * SBLK + blk] = hd[b];
            Ps[b * SBLK + blk] = hs[b];
        }
    } else {
        int t = (blk - SBLK) * 1024 + threadIdx.x;
        const int stride = NB_PREP * 1024;
        for (int i = t; i < 128 * 128; i += stride) {
            int c = i >> 7, k = i & 127;
            __hip_bfloat16 v = __float2bfloat16(W1[k * 128 + c]);
            Wt1[i] = *(unsigned short*)&v;
        }
        for (int i = t; i < 64 * 128; i += stride) {
            int c = i >> 7, k = i & 127;
            __hip_bfloat16 v = __float2bfloat16(W2[k * 64 + c]);
            Wt2[i] = *(unsigned short*)&v;
        }
        for (int i = t; i < N_GRAPHS * 64; i += stride) part[i] = 0.f;   // pooling accumulator
    }
}

// ---------------- phase 2a: per-bucket scan across blocks (exclusive), emit totals ----------------
__global__ __launch_bounds__(SBLK) void k_scanA(int* __restrict__ Pd, int* __restrict__ Ps,
                                                int* __restrict__ Td, int* __restrict__ Ts) {
    __shared__ int sc[SBLK];
    const int b = blockIdx.x;
    const int t = threadIdx.x;
    int* P = (b < NBUCK) ? Pd : Ps;
    int* T = (b < NBUCK) ? Td : Ts;
    const int bb = (b < NBUCK) ? b : b - NBUCK;
    int v = P[bb * SBLK + t];
    sc[t] = v;
    __syncthreads();
    for (int off = 1; off < SBLK; off <<= 1) {
        int u = (t >= off) ? sc[t - off] : 0;
        __syncthreads();
        sc[t] += u;
        __syncthreads();
    }
    P[bb * SBLK + t] = sc[t] - v;    // exclusive within bucket
    if (t == SBLK - 1) T[bb] = sc[SBLK - 1];
}

// ---------------- phase 2b: scan bucket totals -> global bases (with total at [NBUCK]) ----------------
__global__ __launch_bounds__(1024) void k_scanB(const int* __restrict__ Td, const int* __restrict__ Ts,
                                                int* __restrict__ Bd, int* __restrict__ Bs) {
    __shared__ int sc[1024];
    const int t = threadIdx.x;
    int v = (t < NBUCK) ? Td[t] : 0;
    sc[t] = v;
    __syncthreads();
    for (int off = 1; off < 1024; off <<= 1) {
        int u = (t >= off) ? sc[t - off] : 0;
        __syncthreads();
        sc[t] += u;
        __syncthreads();
    }
    if (t < NBUCK) Bd[t] = sc[t] - v;
    if (t == NBUCK - 1) Bd[NBUCK] = sc[t];
    __syncthreads();
    int v2 = (t < NBUCK) ? Ts[t] : 0;
    sc[t] = v2;
    __syncthreads();
    for (int off = 1; off < 1024; off <<= 1) {
        int u = (t >= off) ? sc[t - off] : 0;
        __syncthreads();
        sc[t] += u;
        __syncthreads();
    }
    if (t < NBUCK) Bs[t] = sc[t] - v2;
    if (t == NBUCK - 1) Bs[NBUCK] = sc[t];
}

// ---------------- phase 3: bucketed scatter with FUSED ABSOLUTE TICKETS ----------------
__global__ __launch_bounds__(1024) void k_scatter(const int* __restrict__ src, const int* __restrict__ dst,
                                                  const int* __restrict__ Pd, const int* __restrict__ Ps,
                                                  const int* __restrict__ Bd, const int* __restrict__ Bs,
                                                  unsigned int* __restrict__ pb, unsigned char* __restrict__ sb) {
    __shared__ int tk[NBUCK];
    const int b = blockIdx.x;
    const bool isPb = b < SBLK;
    const int blk = isPb ? b : b - SBLK;
    if (isPb) {
        for (int i = threadIdx.x; i < NBUCK; i += 1024) tk[i] = Bd[i] + Pd[i * SBLK + blk];
    } else {
        for (int i = threadIdx.x; i < NBUCK; i += 1024) tk[i] = Bs[i] + Ps[i * SBLK + blk];
    }
    __syncthreads();
    const int base = blk * EPB;
    if (isPb) {
        for (int i = threadIdx.x; i < EPB; i += 1024) {
            int d = dst[base + i];
            int s = src[base + i];
            int bd = d >> BSH;
            int pos = atomicAdd(&tk[bd], 1);
            pb[pos] = ((unsigned)s << 7) | (unsigned)(d & 127);
        }
    } else {
        for (int i = threadIdx.x; i < EPB; i += 1024) {
            int s = src[base + i];
            int bs = s >> BSH;
            int pos = atomicAdd(&tk[bs], 1);
            sb[pos] = (unsigned char)(s & 127);
        }
    }
}

// ---------------- phase 4: tight CSR (cols+rp) + cnt_out per 128-node bucket ----------------
__global__ __launch_bounds__(256) void k_finalize(const unsigned int* __restrict__ pb, const int* __restrict__ Bd,
                                                  const unsigned char* __restrict__ sb, const int* __restrict__ Bs,
                                                  int* __restrict__ rp, int* __restrict__ cnt_out,
                                                  int* __restrict__ cols) {
    __shared__ int cnt[128];
    __shared__ int exc[128];
    __shared__ int tick[128];
    __shared__ int h[128];
    __shared__ int sc[128];
    const int b = blockIdx.x;
    const int tid = threadIdx.x;
    if (tid < 128) { cnt[tid] = 0; tick[tid] = 0; h[tid] = 0; }
    __syncthreads();
    const int e0 = Bd[b], e1 = Bd[b + 1];
    for (int i = e0 + tid; i < e1; i += 256) atomicAdd(&cnt[pb[i] & 127], 1);
    const int f0 = Bs[b], f1 = Bs[b + 1];
    for (int i = f0 + tid; i < f1; i += 256) atomicAdd(&h[sb[i]], 1);
    __syncthreads();
    if (tid < 128) sc[tid] = cnt[tid];
    __syncthreads();
    for (int off = 1; off < 128; off <<= 1) {
        int u = (tid < 128 && tid >= off) ? sc[tid - off] : 0;
        __syncthreads();
        if (tid < 128) sc[tid] += u;
        __syncthreads();
    }
    if (tid < 128) exc[tid] = sc[tid] - cnt[tid];
    __syncthreads();
    const int node0 = b << BSH;
    if (tid < 128 && node0 + tid < N_NODES) {
        rp[node0 + tid] = e0 + exc[tid];
        cnt_out[node0 + tid] = h[tid];
    }
    if (b == NBUCK - 1 && tid == 0) rp[N_NODES] = N_EDGES;
    for (int i = e0 + tid; i < e1; i += 256) {
        unsigned int p = pb[i];
        int loc = p & 127;
        int t = atomicAdd(&tick[loc], 1);
        cols[e0 + exc[loc] + t] = (int)(p >> 7);
    }
}

// ---------------- layer-1 GEMM: all 128 output cols per block (feats read ONCE) ----------------
// G1[v, 0..127] = rsqrt(deg_out[v]) * (X[v,:] @ W1), fp8 e4m3 packed bytes, row stride 128 B.
__global__ __launch_bounds__(256) void k_gemm1(const float* __restrict__ X,
                                               const unsigned short* __restrict__ Wt,
                                               const int* __restrict__ cnt_out,
                                               unsigned char* __restrict__ Gout) {
    __shared__ __align__(16) unsigned short Xs[32 * XPAD];   // 8.7 KB
    __shared__ __align__(16) unsigned short Ws[128 * XPAD];  // 34.8 KB
    const int tid = threadIdx.x;
    const int row0 = blockIdx.x * 32;  // N_NODES % 32 == 0

    {
        const float4* X4 = (const float4*)X;  // row = 32 float4
#pragma unroll
        for (int j = 0; j < 4; j++) {
            int i = tid + 256 * j;
            int r = i >> 5, k4 = i & 31;
            float4 x = X4[(size_t)(row0 + r) * 32 + k4];
            __hip_bfloat162 lo = __float22bfloat162_rn({x.x, x.y});
            __hip_bfloat162 hi = __float22bfloat162_rn({x.z, x.w});
            uint2 u;
            u.x = *(unsigned int*)&lo;
            u.y = *(unsigned int*)&hi;
            *(uint2*)&Xs[r * XPAD + k4 * 4] = u;
        }
    }
    {
        const uint2* W2 = (const uint2*)Wt;  // row = 32 uint2
#pragma unroll
        for (int j = 0; j < 16; j++) {
            int i = tid + 256 * j;
            int cc = i >> 5, kk = i & 31;
            uint2 u = W2[(size_t)cc * 32 + kk];
            *(uint2*)&Ws[cc * XPAD + kk * 4] = u;
        }
    }
    __syncthreads();

    const int lane = tid & 63;
    const int wv = tid >> 6;        // wave -> 32-col group
    const int m = lane & 15;
    const int q = lane >> 4;
    const int cg = wv * 32;

    f32x4 acc00 = {0.f, 0.f, 0.f, 0.f}, acc01 = {0.f, 0.f, 0.f, 0.f};
    f32x4 acc10 = {0.f, 0.f, 0.f, 0.f}, acc11 = {0.f, 0.f, 0.f, 0.f};
#pragma unroll
    for (int ks = 0; ks < 4; ks++) {
        int kb = ks * 32 + q * 8;
        bf16x8 a0 = *(const bf16x8*)&Xs[m * XPAD + kb];
        bf16x8 a1 = *(const bf16x8*)&Xs[(16 + m) * XPAD + kb];
        bf16x8 b0 = *(const bf16x8*)&Ws[(cg + m) * XPAD + kb];
        bf16x8 b1 = *(const bf16x8*)&Ws[(cg + 16 + m) * XPAD + kb];
        acc00 = __builtin_amdgcn_mfma_f32_16x16x32_bf16(a0, b0, acc00, 0, 0, 0);
        acc01 = __builtin_amdgcn_mfma_f32_16x16x32_bf16(a0, b1, acc01, 0, 0, 0);
        acc10 = __builtin_amdgcn_mfma_f32_16x16x32_bf16(a1, b0, acc10, 0, 0, 0);
        acc11 = __builtin_amdgcn_mfma_f32_16x16x32_bf16(a1, b1, acc11, 0, 0, 0);
    }
#pragma unroll
    for (int r = 0; r < 4; r++) {
        int rowA = row0 + q * 4 + r;
        int rowB = rowA + 16;
        float sA = rsqrtf((float)max(cnt_out[rowA], 1));
        float sB = rsqrtf((float)max(cnt_out[rowB], 1));
        unsigned int pkA = __builtin_amdgcn_cvt_pk_fp8_f32(acc00[r] * sA, acc01[r] * sA, 0, false);
        unsigned int pkB = __builtin_amdgcn_cvt_pk_fp8_f32(acc10[r] * sB, acc11[r] * sB, 0, false);
        unsigned char* gA = Gout + (size_t)rowA * 128 + cg + m;
        gA[0]  = (unsigned char)(pkA & 0xffu);
        gA[16] = (unsigned char)((pkA >> 8) & 0xffu);
        unsigned char* gB = Gout + (size_t)rowB * 128 + cg + m;
        gB[0]  = (unsigned char)(pkB & 0xffu);
        gB[16] = (unsigned char)((pkB >> 8) & 0xffu);
    }
}

// ================= SpMM column-per-lane helpers (scalar cols, zero cross-lane ops) =================
__device__ __forceinline__ void tail128(const unsigned short* __restrict__ gl, const int* __restrict__ cols,
                                        int b, int d, int j, f32x2& acc) {
    while (j + 16 <= d) {
        unsigned int u[16];
#pragma unroll
        for (int k = 0; k < 16; k++) { int s = cols[b + j + k]; u[k] = gl[(size_t)s * 64]; }
#pragma unroll
        for (int k = 0; k < 16; k++) acc += __builtin_amdgcn_cvt_pk_f32_fp8(u[k], false);
        j += 16;
    }
    if (j + 8 <= d) {
        unsigned int u[8];
#pragma unroll
        for (int k = 0; k < 8; k++) { int s = cols[b + j + k]; u[k] = gl[(size_t)s * 64]; }
#pragma unroll
        for (int k = 0; k < 8; k++) acc += __builtin_amdgcn_cvt_pk_f32_fp8(u[k], false);
        j += 8;
    }
    if (j + 4 <= d) {
        unsigned int u[4];
#pragma unroll
        for (int k = 0; k < 4; k++) { int s = cols[b + j + k]; u[k] = gl[(size_t)s * 64]; }
#pragma unroll
        for (int k = 0; k < 4; k++) acc += __builtin_amdgcn_cvt_pk_f32_fp8(u[k], false);
        j += 4;
    }
    if (j + 2 <= d) {
        unsigned int u0, u1;
        { int s = cols[b + j];     u0 = gl[(size_t)s * 64]; }
        { int s = cols[b + j + 1]; u1 = gl[(size_t)s * 64]; }
        acc += __builtin_amdgcn_cvt_pk_f32_fp8(u0, false);
        acc += __builtin_amdgcn_cvt_pk_f32_fp8(u1, false);
        j += 2;
    }
    if (j < d) {
        int s = cols[b + j];
        unsigned int u = gl[(size_t)s * 64];
        acc += __builtin_amdgcn_cvt_pk_f32_fp8(u, false);
    }
}

__device__ __forceinline__ void tail64(const unsigned char* __restrict__ gl, const int* __restrict__ cols,
                                       int b, int d, int j, f32x2& acc) {
    while (j + 16 <= d) {
        unsigned int u[16];
#pragma unroll
        for (int k = 0; k < 16; k++) { int s = cols[b + j + k]; u[k] = gl[(size_t)s * 64]; }
#pragma unroll
        for (int k = 0; k < 16; k++) acc += __builtin_amdgcn_cvt_pk_f32_fp8(u[k], false);
        j += 16;
    }
    if (j + 8 <= d) {
        unsigned int u[8];
#pragma unroll
        for (int k = 0; k < 8; k++) { int s = cols[b + j + k]; u[k] = gl[(size_t)s * 64]; }
#pragma unroll
        for (int k = 0; k < 8; k++) acc += __builtin_amdgcn_cvt_pk_f32_fp8(u[k], false);
        j += 8;
    }
    if (j + 4 <= d) {
        unsigned int u[4];
#pragma unroll
        for (int k = 0; k < 4; k++) { int s = cols[b + j + k]; u[k] = gl[(size_t)s * 64]; }
#pragma unroll
        for (int k = 0; k < 4; k++) acc += __builtin_amdgcn_cvt_pk_f32_fp8(u[k], false);
        j += 4;
    }
    if (j + 2 <= d) {
        unsigned int u0, u1;
        { int s = cols[b + j];     u0 = gl[(size_t)s * 64]; }
        { int s = cols[b + j + 1]; u1 = gl[(size_t)s * 64]; }
        acc += __builtin_amdgcn_cvt_pk_f32_fp8(u0, false);
        acc += __builtin_amdgcn_cvt_pk_f32_fp8(u1, false);
        j += 2;
    }
    if (j < d) {
        int s = cols[b + j];
        unsigned int u = gl[(size_t)s * 64];
        acc += __builtin_amdgcn_cvt_pk_f32_fp8(u, false);
    }
}

// ================= FUSED SpMM F=128 fp8 + layer-2 GEMM: h1 never touches HBM =================
// Block = 4 waves = 8 nodes. Each wave gathers 2 nodes (column-per-lane, 2 cols/lane), computes the
// bf16 h1 rows, stages them in LDS hs[16][XPAD] (rows 8..15 zero). After one barrier, each wave runs
// a 16x16 MFMA tile (K=128) against W2t staged in LDS and writes g2 fp8 directly (output rows 0..7).
// Deletes the 25.6MB h1 write + 25.6MB read and the whole k_gemm_mfma kernel. Numerics identical.
__global__ __launch_bounds__(256) void k_spmm128f8(const unsigned short* __restrict__ G,
                                                   const int* __restrict__ rp,
                                                   const int* __restrict__ cols,
                                                   const float* __restrict__ bias,
                                                   const int* __restrict__ cnt_out,
                                                   const unsigned short* __restrict__ Wt,
                                                   unsigned char* __restrict__ G2out) {
    __shared__ __align__(16) unsigned short hs[16 * XPAD];   // 4.3 KB (rows 8..15 zero)
    __shared__ __align__(16) unsigned short Ws[64 * XPAD];   // 17.4 KB
    const int tid = threadIdx.x;
    const int lane = tid & 63;
    const int wave = tid >> 6;
    const int vb = blockIdx.x * 8;                // grid = N_NODES/8
    const int v0 = vb + wave * 2;

    // stage W2t (64 cols x 128 k) and zero the unused A rows
    {
        const uint2* W2 = (const uint2*)Wt;  // row = 32 uint2
#pragma unroll
        for (int j = 0; j < 8; j++) {
            int i = tid + 256 * j;
            int c = i >> 5, kk = i & 31;
            uint2 u = W2[(size_t)c * 32 + kk];
            *(uint2*)&Ws[c * XPAD + kk * 4] = u;
        }
    }
    for (int i = tid; i < 8 * XPAD; i += 256) hs[8 * XPAD + i] = 0;

    const int b0 = __builtin_amdgcn_readfirstlane(rp[v0]);
    const int b1 = __builtin_amdgcn_readfirstlane(rp[v0 + 1]);
    const int e1 = __builtin_amdgcn_readfirstlane(rp[v0 + 2]);
    const int dA = b1 - b0, dB = e1 - b1;
    const unsigned short* gl = G + lane;          // row = 64 ushorts
    f32x2 aA = {0.f, 0.f}, aB = {0.f, 0.f};
    int ja = 0, jb = 0;
    while (ja + 8 <= dA && jb + 8 <= dB) {
        unsigned int u[8], w[8];
#pragma unroll
        for (int k = 0; k < 8; k++) { int s = cols[b0 + ja + k]; u[k] = gl[(size_t)s * 64]; }
#pragma unroll
        for (int k = 0; k < 8; k++) { int s = cols[b1 + jb + k]; w[k] = gl[(size_t)s * 64]; }
#pragma unroll
        for (int k = 0; k < 8; k++) aA += __builtin_amdgcn_cvt_pk_f32_fp8(u[k], false);
#pragma unroll
        for (int k = 0; k < 8; k++) aB += __builtin_amdgcn_cvt_pk_f32_fp8(w[k], false);
        ja += 8; jb += 8;
    }
    tail128(gl, cols, b0, dA, ja, aA);
    tail128(gl, cols, b1, dB, jb, aB);

    const float2 bb = *(const float2*)&bias[2 * lane];
    {
        const float rs = rsqrtf((float)max(dA, 1));
        __hip_bfloat162 p = __float22bfloat162_rn({fmaxf(fmaf(aA.x, rs, bb.x), 0.f),
                                                   fmaxf(fmaf(aA.y, rs, bb.y), 0.f)});
        *(unsigned int*)&hs[(wave * 2) * XPAD + 2 * lane] = *(unsigned int*)&p;
    }
    {
        const float rs = rsqrtf((float)max(dB, 1));
        __hip_bfloat162 p = __float22bfloat162_rn({fmaxf(fmaf(aB.x, rs, bb.x), 0.f),
                                                   fmaxf(fmaf(aB.y, rs, bb.y), 0.f)});
        *(unsigned int*)&hs[(wave * 2 + 1) * XPAD + 2 * lane] = *(unsigned int*)&p;
    }
    __syncthreads();

    // layer-2 GEMM: 8 valid rows x 128 K @ W2 -> 64 cols; wave owns cols [wave*16, wave*16+16)
    const int m = lane & 15;
    const int q = lane >> 4;
    const int coff = wave * 16;
    f32x4 acc = {0.f, 0.f, 0.f, 0.f};
#pragma unroll
    for (int ks = 0; ks < 4; ks++) {
        int kb = ks * 32 + q * 8;
        bf16x8 a = *(const bf16x8*)&hs[m * XPAD + kb];
        bf16x8 b = *(const bf16x8*)&Ws[(coff + m) * XPAD + kb];
        acc = __builtin_amdgcn_mfma_f32_16x16x32_bf16(a, b, acc, 0, 0, 0);
    }
#pragma unroll
    for (int r = 0; r < 4; r++) {
        int row = q * 4 + r;            // D row; valid rows are 0..7 (q < 2)
        if (row < 8) {
            int node = vb + row;
            float s = rsqrtf((float)max(cnt_out[node], 1));
            float v = acc[r] * s;
            unsigned int pk = __builtin_amdgcn_cvt_pk_fp8_f32(v, v, 0, false);
            G2out[(size_t)node * 64 + coff + m] = (unsigned char)(pk & 0xffu);
        }
    }
}

// ================= SpMM F=64 fp8 + FUSED mean-pool: 2 nodes/wave, 8 nodes/block =================
// Lane owns col `lane`. After bias+ReLU, values are staged in LDS acc[8][64]; consecutive rows
// sharing the same (sorted) gid are run-merged and flushed with one global float atomicAdd per
// run per column (~2 runs/block). h2 is never materialized.
__global__ __launch_bounds__(256) void k_spmm64f8(const unsigned char* __restrict__ G,
                                                  const int* __restrict__ rp,
                                                  const int* __restrict__ cols,
                                                  const float* __restrict__ bias,
                                                  const int* __restrict__ gid,
                                                  float* __restrict__ part) {
    __shared__ float acc[8][64];
    __shared__ int gv[8];
    const int lane = threadIdx.x & 63;
    const int wave = threadIdx.x >> 6;
    const int vb = blockIdx.x * 8;                // block owns 8 consecutive nodes
    const int v0 = vb + wave * 2;
    const int b0 = __builtin_amdgcn_readfirstlane(rp[v0]);
    const int b1 = __builtin_amdgcn_readfirstlane(rp[v0 + 1]);
    const int e1 = __builtin_amdgcn_readfirstlane(rp[v0 + 2]);
    const int dA = b1 - b0, dB = e1 - b1;
    const unsigned char* gl = G + lane;           // row = 64 bytes
    if (threadIdx.x < 8) gv[threadIdx.x] = gid[vb + threadIdx.x];
    f32x2 aA = {0.f, 0.f}, aB = {0.f, 0.f};
    int ja = 0, jb = 0;
    while (ja + 8 <= dA && jb + 8 <= dB) {
        unsigned int u[8], w[8];
#pragma unroll
        for (int k = 0; k < 8; k++) { int s = cols[b0 + ja + k]; u[k] = gl[(size_t)s * 64]; }
#pragma unroll
        for (int k = 0; k < 8; k++) { int s = cols[b1 + jb + k]; w[k] = gl[(size_t)s * 64]; }
#pragma unroll
        for (int k = 0; k < 8; k++) aA += __builtin_amdgcn_cvt_pk_f32_fp8(u[k], false);
#pragma unroll
        for (int k = 0; k < 8; k++) aB += __builtin_amdgcn_cvt_pk_f32_fp8(w[k], false);
        ja += 8; jb += 8;
    }
    tail64(gl, cols, b0, dA, ja, aA);
    tail64(gl, cols, b1, dB, jb, aB);

    const float bbias = bias[lane];
    {
        const float rs = rsqrtf((float)max(dA, 1));
        acc[wave * 2][lane] = fmaxf(fmaf(aA.x, rs, bbias), 0.f);
    }
    {
        const float rs = rsqrtf((float)max(dB, 1));
        acc[wave * 2 + 1][lane] = fmaxf(fmaf(aB.x, rs, bbias), 0.f);
    }
    __syncthreads();
    if (threadIdx.x < 64) {
        const int col = threadIdx.x;
        float sum = acc[0][col];
        int g = gv[0];
#pragma unroll
        for (int r = 1; r < 8; r++) {
            int gr = gv[r];
            float v = acc[r][col];
            if (gr != g) {
                atomicAdd(&part[g * 64 + col], sum);
                sum = v;
                g = gr;
            } else {
                sum += v;
            }
        }
        atomicAdd(&part[g * 64 + col], sum);
    }
}

// ---------------- pooling finish + MLP + softmax (block per graph, 64 thr) ----------------
__global__ __launch_bounds__(64) void k_mlp(const float* __restrict__ part,
                                            const int* __restrict__ gid,
                                            const float* __restrict__ fcW1,
                                            const float* __restrict__ fcb1,
                                            const float* __restrict__ fcW2,
                                            const float* __restrict__ fcb2,
                                            float* __restrict__ out) {
    __shared__ int se[2];
    __shared__ float p[64];
    __shared__ float z[10];
    __shared__ float l[10];
    __shared__ float red[2];
    const int g = blockIdx.x;
    const int t = threadIdx.x;  // 64
    if (t < 2) {
        int target = g + t;
        int lo = 0, hi = N_NODES;
        while (lo < hi) {
            int mid = (lo + hi) >> 1;
            if (gid[mid] < target) lo = mid + 1; else hi = mid;
        }
        se[t] = lo;
    }
    __syncthreads();
    const int cnt = max(se[1] - se[0], 1);
    p[t] = part[g * 64 + t] / (float)cnt;
    __syncthreads();
    if (t < 10) {
        float acc = fcb1[t];
        for (int k = 0; k < 64; k++) acc = fmaf(p[k], fcW1[k * 10 + t], acc);
        z[t] = fmaxf(acc, 0.f);
    }
    __syncthreads();
    if (t < 10) {
        float acc = fcb2[t];
        for (int k = 0; k < 10; k++) acc = fmaf(z[k], fcW2[k * 10 + t], acc);
        l[t] = acc;
    }
    __syncthreads();
    if (t == 0) {
        float m = l[0];
        for (int i = 1; i < 10; i++) m = fmaxf(m, l[i]);
        float ssum = 0.f;
        for (int i = 0; i < 10; i++) ssum += expf(l[i] - m);
        red[0] = m;
        red[1] = ssum;
    }
    __syncthreads();
    if (t < 10) out[g * 10 + t] = expf(l[t] - red[0]) / red[1];
}

// ---------------- host ----------------
extern "C" void kernel_launch(void* const* d_in, const int* in_sizes, int n_in,
                              void* d_out, int out_size, void* d_ws, size_t ws_size,
                              hipStream_t stream) {
    const float* feats = (const float*)d_in[0];
    const int* src = (const int*)d_in[1];
    const int* dst = (const int*)d_in[2];
    const int* gid = (const int*)d_in[3];
    const float* W1 = (const float*)d_in[4];
    const float* b1 = (const float*)d_in[5];
    const float* W2 = (const float*)d_in[6];
    const float* b2 = (const float*)d_in[7];
    const float* fcW1 = (const float*)d_in[8];
    const float* fcb1 = (const float*)d_in[9];
    const float* fcW2 = (const float*)d_in[10];
    const float* fcb2 = (const float*)d_in[11];
    float* out = (float*)d_out;

    char* w = (char*)d_ws;
    size_t off = 0;
    auto alloc = [&](size_t bytes) -> void* {
        void* p = w + off;
        off = (off + bytes + 255) & ~(size_t)255;
        return p;
    };
    int* cnt_out = (int*)alloc(N_NODES * 4);
    int* rp      = (int*)alloc((N_NODES + 1) * 4);
    int* cols    = (int*)alloc((size_t)N_EDGES * 4);                         // 6.4 MB tight CSR
    int* Pd      = (int*)alloc(NBUCK * SBLK * 4);                            // 400 KB
    int* Ps      = (int*)alloc(NBUCK * SBLK * 4);
    int* Td      = (int*)alloc(NBUCK * 4);
    int* Ts      = (int*)alloc(NBUCK * 4);
    int* Bd      = (int*)alloc((NBUCK + 1) * 4);
    int* Bs      = (int*)alloc((NBUCK + 1) * 4);
    unsigned int* pb  = (unsigned int*)alloc((size_t)N_EDGES * 4);           // 6.4 MB packed
    unsigned char* sb = (unsigned char*)alloc((size_t)N_EDGES);              // 1.6 MB
    unsigned short* Wt1 = (unsigned short*)alloc(128 * 128 * 2);
    unsigned short* Wt2 = (unsigned short*)alloc(64 * 128 * 2);
    unsigned char* g1 = (unsigned char*)alloc((size_t)N_NODES * 128);        // fp8 e4m3, 12.8 MB
    unsigned char* g2 = (unsigned char*)alloc((size_t)N_NODES * 64);         // fp8 e4m3, 6.4 MB
    float* part = (float*)alloc((size_t)N_GRAPHS * 64 * 4);                  // 32 KB pooling accumulator

    // build pipeline (bucket sort both sides; fused absolute tickets in scatter; part zeroed in hist2)
    k_hist2<<<SBLK + NB_PREP, 1024, 0, stream>>>(src, dst, Pd, Ps, W1, W2, Wt1, Wt2, part);
    k_scanA<<<2 * NBUCK, SBLK, 0, stream>>>(Pd, Ps, Td, Ts);
    k_scanB<<<1, 1024, 0, stream>>>(Td, Ts, Bd, Bs);
    k_scatter<<<2 * SBLK, 1024, 0, stream>>>(src, dst, Pd, Ps, Bd, Bs, pb, sb);
    k_finalize<<<NBUCK, 256, 0, stream>>>(pb, Bd, sb, Bs, rp, cnt_out, cols);

    // layer 1 (g1 fp8): single pass over feats, all 128 output cols per block
    k_gemm1<<<N_NODES / 32, 256, 0, stream>>>(feats, Wt1, cnt_out, g1);

    // fused: spmm(g1) -> h1 (LDS only) -> layer-2 GEMM -> g2 fp8
    k_spmm128f8<<<N_NODES / 8, 256, 0, stream>>>((const unsigned short*)g1, rp, cols, b1, cnt_out, Wt2, g2);

    // layer 2 aggregation + fused mean-pool into part
    k_spmm64f8<<<N_NODES / 8, 256, 0, stream>>>(g2, rp, cols, b2, gid, part);

    // MLP + softmax (reads pooled accumulator directly)
    k_mlp<<<N_GRAPHS, 64, 0, stream>>>(part, gid, fcW1, fcb1, fcW2, fcb2, out);
}

// Round 13
// 258.232 us; speedup vs baseline: 1.0323x; 1.0323x over previous
//
#include <hip/hip_runtime.h>
#include <hip/hip_bf16.h>

#define N_NODES 100000
#define N_EDGES 1600000
#define N_GRAPHS 128
#define IN_F 128
#define H_F 128
#define OUT_F 64
#define HID 10
#define NCLS 10
#define XPAD 136    // LDS row stride in bf16 (pad 128 -> 136: 16-way conflict -> free 2-way)
#define BSH 7                     // bucket = node >> 7 (128-node windows)
#define NBUCK 782                 // ceil(100000/128)
#define SBLK 128                  // edge partitions for hist/scatter
#define EPB (N_EDGES / SBLK)      // 12500, exact
#define NB_PREP 4

typedef __attribute__((ext_vector_type(8))) short bf16x8;
typedef __attribute__((ext_vector_type(4))) float f32x4;
typedef __attribute__((ext_vector_type(2))) float f32x2;

__device__ __forceinline__ float bl(unsigned int u) { return __uint_as_float(u << 16); }
__device__ __forceinline__ float bh(unsigned int u) { return __uint_as_float(u & 0xffff0000u); }

// ---------------- phase 1: LDS-privatized bucket histograms (dst & src) + weight prep + part zero ----------------
__global__ __launch_bounds__(1024) void k_hist2(const int* __restrict__ src, const int* __restrict__ dst,
                                                int* __restrict__ Pd, int* __restrict__ Ps,
                                                const float* __restrict__ W1, const float* __restrict__ W2,
                                                unsigned short* __restrict__ Wt1, unsigned short* __restrict__ Wt2,
                                                float* __restrict__ part) {
    __shared__ int hd[NBUCK];
    __shared__ int hs[NBUCK];
    const int blk = blockIdx.x;
    if (blk < SBLK) {
        for (int i = threadIdx.x; i < NBUCK; i += 1024) { hd[i] = 0; hs[i] = 0; }
        __syncthreads();
        const int base = blk * EPB;
        for (int i = threadIdx.x; i < EPB; i += 1024) {
            atomicAdd(&hd[dst[base + i] >> BSH], 1);
            atomicAdd(&hs[src[base + i] >> BSH], 1);
        }
        __syncthreads();
        for (int b = threadIdx.x; b < NBUCK; b += 1024) {
            Pd[b * SBLK + blk] = hd[b];
            Ps[b * SBLK + blk] = hs[b];
        }
    } else {
        int t = (blk - SBLK) * 1024 + threadIdx.x;
        const int stride = NB_PREP * 1024;
        for (int i = t; i < 128 * 128; i += stride) {
            int c = i >> 7, k = i & 127;
            __hip_bfloat16 v = __float2bfloat16(W1[k * 128 + c]);
            Wt1[i] = *(unsigned short*)&v;
        }
        for (int i = t; i < 64 * 128; i += stride) {
            int c = i >> 7, k = i & 127;
            __hip_bfloat16 v = __float2bfloat16(W2[k * 64 + c]);
            Wt2[i] = *(unsigned short*)&v;
        }
        for (int i = t; i < N_GRAPHS * 64; i += stride) part[i] = 0.f;   // pooling accumulator
    }
}

// ---------------- phase 2a: per-bucket scan across blocks (exclusive), emit totals ----------------
__global__ __launch_bounds__(SBLK) void k_scanA(int* __restrict__ Pd, int* __restrict__ Ps,
                                                int* __restrict__ Td, int* __restrict__ Ts) {
    __shared__ int sc[SBLK];
    const int b = blockIdx.x;
    const int t = threadIdx.x;
    int* P = (b < NBUCK) ? Pd : Ps;
    int* T = (b < NBUCK) ? Td : Ts;
    const int bb = (b < NBUCK) ? b : b - NBUCK;
    int v = P[bb * SBLK + t];
    sc[t] = v;
    __syncthreads();
    for (int off = 1; off < SBLK; off <<= 1) {
        int u = (t >= off) ? sc[t - off] : 0;
        __syncthreads();
        sc[t] += u;
        __syncthreads();
    }
    P[bb * SBLK + t] = sc[t] - v;    // exclusive within bucket
    if (t == SBLK - 1) T[bb] = sc[SBLK - 1];
}

// ---------------- phase 2b: scan bucket totals -> global bases (with total at [NBUCK]) ----------------
__global__ __launch_bounds__(1024) void k_scanB(const int* __restrict__ Td, const int* __restrict__ Ts,
                                                int* __restrict__ Bd, int* __restrict__ Bs) {
    __shared__ int sc[1024];
    const int t = threadIdx.x;
    int v = (t < NBUCK) ? Td[t] : 0;
    sc[t] = v;
    __syncthreads();
    for (int off = 1; off < 1024; off <<= 1) {
        int u = (t >= off) ? sc[t - off] : 0;
        __syncthreads();
        sc[t] += u;
        __syncthreads();
    }
    if (t < NBUCK) Bd[t] = sc[t] - v;
    if (t == NBUCK - 1) Bd[NBUCK] = sc[t];
    __syncthreads();
    int v2 = (t < NBUCK) ? Ts[t] : 0;
    sc[t] = v2;
    __syncthreads();
    for (int off = 1; off < 1024; off <<= 1) {
        int u = (t >= off) ? sc[t - off] : 0;
        __syncthreads();
        sc[t] += u;
        __syncthreads();
    }
    if (t < NBUCK) Bs[t] = sc[t] - v2;
    if (t == NBUCK - 1) Bs[NBUCK] = sc[t];
}

// ---------------- phase 3: bucketed scatter with FUSED ABSOLUTE TICKETS ----------------
// tk[bucket] is initialized to the absolute output base (Bd+Pd / Bs+Ps) for this block's segment,
// so the per-edge LDS atomicAdd returns the final address directly: no per-edge Bd/Pd loads.
__global__ __launch_bounds__(1024) void k_scatter(const int* __restrict__ src, const int* __restrict__ dst,
                                                  const int* __restrict__ Pd, const int* __restrict__ Ps,
                                                  const int* __restrict__ Bd, const int* __restrict__ Bs,
                                                  unsigned int* __restrict__ pb, unsigned char* __restrict__ sb) {
    __shared__ int tk[NBUCK];
    const int b = blockIdx.x;
    const bool isPb = b < SBLK;
    const int blk = isPb ? b : b - SBLK;
    if (isPb) {
        for (int i = threadIdx.x; i < NBUCK; i += 1024) tk[i] = Bd[i] + Pd[i * SBLK + blk];
    } else {
        for (int i = threadIdx.x; i < NBUCK; i += 1024) tk[i] = Bs[i] + Ps[i * SBLK + blk];
    }
    __syncthreads();
    const int base = blk * EPB;
    if (isPb) {
        for (int i = threadIdx.x; i < EPB; i += 1024) {
            int d = dst[base + i];
            int s = src[base + i];
            int bd = d >> BSH;
            int pos = atomicAdd(&tk[bd], 1);
            pb[pos] = ((unsigned)s << 7) | (unsigned)(d & 127);
        }
    } else {
        for (int i = threadIdx.x; i < EPB; i += 1024) {
            int s = src[base + i];
            int bs = s >> BSH;
            int pos = atomicAdd(&tk[bs], 1);
            sb[pos] = (unsigned char)(s & 127);
        }
    }
}

// ---------------- phase 4: tight CSR (cols+rp) + cnt_out per 128-node bucket ----------------
__global__ __launch_bounds__(256) void k_finalize(const unsigned int* __restrict__ pb, const int* __restrict__ Bd,
                                                  const unsigned char* __restrict__ sb, const int* __restrict__ Bs,
                                                  int* __restrict__ rp, int* __restrict__ cnt_out,
                                                  int* __restrict__ cols) {
    __shared__ int cnt[128];
    __shared__ int exc[128];
    __shared__ int tick[128];
    __shared__ int h[128];
    __shared__ int sc[128];
    const int b = blockIdx.x;
    const int tid = threadIdx.x;
    if (tid < 128) { cnt[tid] = 0; tick[tid] = 0; h[tid] = 0; }
    __syncthreads();
    const int e0 = Bd[b], e1 = Bd[b + 1];
    for (int i = e0 + tid; i < e1; i += 256) atomicAdd(&cnt[pb[i] & 127], 1);
    const int f0 = Bs[b], f1 = Bs[b + 1];
    for (int i = f0 + tid; i < f1; i += 256) atomicAdd(&h[sb[i]], 1);
    __syncthreads();
    if (tid < 128) sc[tid] = cnt[tid];
    __syncthreads();
    for (int off = 1; off < 128; off <<= 1) {
        int u = (tid < 128 && tid >= off) ? sc[tid - off] : 0;
        __syncthreads();
        if (tid < 128) sc[tid] += u;
        __syncthreads();
    }
    if (tid < 128) exc[tid] = sc[tid] - cnt[tid];
    __syncthreads();
    const int node0 = b << BSH;
    if (tid < 128 && node0 + tid < N_NODES) {
        rp[node0 + tid] = e0 + exc[tid];
        cnt_out[node0 + tid] = h[tid];
    }
    if (b == NBUCK - 1 && tid == 0) rp[N_NODES] = N_EDGES;
    for (int i = e0 + tid; i < e1; i += 256) {
        unsigned int p = pb[i];
        int loc = p & 127;
        int t = atomicAdd(&tick[loc], 1);
        cols[e0 + exc[loc] + t] = (int)(p >> 7);
    }
}

// ---------------- layer-1 GEMM: all 128 output cols per block (feats read ONCE) ----------------
// G1[v, 0..127] = rsqrt(deg_out[v]) * (X[v,:] @ W1), fp8 e4m3 packed bytes, row stride 128 B.
__global__ __launch_bounds__(256) void k_gemm1(const float* __restrict__ X,
                                               const unsigned short* __restrict__ Wt,
                                               const int* __restrict__ cnt_out,
                                               unsigned char* __restrict__ Gout) {
    __shared__ __align__(16) unsigned short Xs[32 * XPAD];   // 8.7 KB
    __shared__ __align__(16) unsigned short Ws[128 * XPAD];  // 34.8 KB
    const int tid = threadIdx.x;
    const int row0 = blockIdx.x * 32;  // N_NODES % 32 == 0

    {
        const float4* X4 = (const float4*)X;  // row = 32 float4
#pragma unroll
        for (int j = 0; j < 4; j++) {
            int i = tid + 256 * j;
            int r = i >> 5, k4 = i & 31;
            float4 x = X4[(size_t)(row0 + r) * 32 + k4];
            __hip_bfloat162 lo = __float22bfloat162_rn({x.x, x.y});
            __hip_bfloat162 hi = __float22bfloat162_rn({x.z, x.w});
            uint2 u;
            u.x = *(unsigned int*)&lo;
            u.y = *(unsigned int*)&hi;
            *(uint2*)&Xs[r * XPAD + k4 * 4] = u;
        }
    }
    {
        const uint2* W2 = (const uint2*)Wt;  // row = 32 uint2
#pragma unroll
        for (int j = 0; j < 16; j++) {
            int i = tid + 256 * j;
            int cc = i >> 5, kk = i & 31;
            uint2 u = W2[(size_t)cc * 32 + kk];
            *(uint2*)&Ws[cc * XPAD + kk * 4] = u;
        }
    }
    __syncthreads();

    const int lane = tid & 63;
    const int wv = tid >> 6;        // wave -> 32-col group
    const int m = lane & 15;
    const int q = lane >> 4;
    const int cg = wv * 32;

    f32x4 acc00 = {0.f, 0.f, 0.f, 0.f}, acc01 = {0.f, 0.f, 0.f, 0.f};
    f32x4 acc10 = {0.f, 0.f, 0.f, 0.f}, acc11 = {0.f, 0.f, 0.f, 0.f};
#pragma unroll
    for (int ks = 0; ks < 4; ks++) {
        int kb = ks * 32 + q * 8;
        bf16x8 a0 = *(const bf16x8*)&Xs[m * XPAD + kb];
        bf16x8 a1 = *(const bf16x8*)&Xs[(16 + m) * XPAD + kb];
        bf16x8 b0 = *(const bf16x8*)&Ws[(cg + m) * XPAD + kb];
        bf16x8 b1 = *(const bf16x8*)&Ws[(cg + 16 + m) * XPAD + kb];
        acc00 = __builtin_amdgcn_mfma_f32_16x16x32_bf16(a0, b0, acc00, 0, 0, 0);
        acc01 = __builtin_amdgcn_mfma_f32_16x16x32_bf16(a0, b1, acc01, 0, 0, 0);
        acc10 = __builtin_amdgcn_mfma_f32_16x16x32_bf16(a1, b0, acc10, 0, 0, 0);
        acc11 = __builtin_amdgcn_mfma_f32_16x16x32_bf16(a1, b1, acc11, 0, 0, 0);
    }
#pragma unroll
    for (int r = 0; r < 4; r++) {
        int rowA = row0 + q * 4 + r;
        int rowB = rowA + 16;
        float sA = rsqrtf((float)max(cnt_out[rowA], 1));
        float sB = rsqrtf((float)max(cnt_out[rowB], 1));
        unsigned int pkA = __builtin_amdgcn_cvt_pk_fp8_f32(acc00[r] * sA, acc01[r] * sA, 0, false);
        unsigned int pkB = __builtin_amdgcn_cvt_pk_fp8_f32(acc10[r] * sB, acc11[r] * sB, 0, false);
        unsigned char* gA = Gout + (size_t)rowA * 128 + cg + m;
        gA[0]  = (unsigned char)(pkA & 0xffu);
        gA[16] = (unsigned char)((pkA >> 8) & 0xffu);
        unsigned char* gB = Gout + (size_t)rowB * 128 + cg + m;
        gB[0]  = (unsigned char)(pkB & 0xffu);
        gB[16] = (unsigned char)((pkB >> 8) & 0xffu);
    }
}

// ---------------- MFMA GEMM (layer 2): G[v, 0..63] = rsqrt(deg_out[v]) * (X[v,:] @ W2) ----------------
template <int TOTF, bool XBF16, bool OUT_FP8>
__global__ __launch_bounds__(256) void k_gemm_mfma(const void* __restrict__ Xv,
                                                   const unsigned short* __restrict__ Wt,
                                                   const int* __restrict__ cnt_out,
                                                   void* __restrict__ GoutV) {
    __shared__ __align__(16) unsigned short Xs[32 * XPAD];
    __shared__ __align__(16) unsigned short Ws[64 * XPAD];
    const int tid = threadIdx.x;
    const int cbase = blockIdx.y * 64;
    const int row0 = blockIdx.x * 32;  // N_NODES % 32 == 0

    if constexpr (XBF16) {
        const uint2* X2 = (const uint2*)Xv;  // row = 32 uint2 (128 bf16)
#pragma unroll
        for (int j = 0; j < 4; j++) {
            int i = tid + 256 * j;
            int r = i >> 5, kk = i & 31;
            uint2 u = X2[(size_t)(row0 + r) * 32 + kk];
            *(uint2*)&Xs[r * XPAD + kk * 4] = u;
        }
    } else {
        const float4* X4 = (const float4*)Xv;  // row = 32 float4
#pragma unroll
        for (int j = 0; j < 4; j++) {
            int i = tid + 256 * j;
            int r = i >> 5, k4 = i & 31;
            float4 x = X4[(size_t)(row0 + r) * 32 + k4];
            __hip_bfloat162 lo = __float22bfloat162_rn({x.x, x.y});
            __hip_bfloat162 hi = __float22bfloat162_rn({x.z, x.w});
            uint2 u;
            u.x = *(unsigned int*)&lo;
            u.y = *(unsigned int*)&hi;
            *(uint2*)&Xs[r * XPAD + k4 * 4] = u;
        }
    }
    {
        const uint2* W2 = (const uint2*)Wt;  // row = 32 uint2
#pragma unroll
        for (int j = 0; j < 8; j++) {
            int i = tid + 256 * j;
            int c = i >> 5, kk = i & 31;
            uint2 u = W2[(size_t)(cbase + c) * 32 + kk];
            *(uint2*)&Ws[c * XPAD + kk * 4] = u;
        }
    }
    __syncthreads();

    const int lane = tid & 63;
    const int wv = tid >> 6;
    const int m = lane & 15;
    const int q = lane >> 4;
    const int roff = (wv & 1) * 16;
    const int coff = (wv >> 1) * 32;

    f32x4 acc0 = {0.f, 0.f, 0.f, 0.f}, acc1 = {0.f, 0.f, 0.f, 0.f};
#pragma unroll
    for (int ks = 0; ks < 4; ks++) {
        int kb = ks * 32 + q * 8;
        bf16x8 a  = *(const bf16x8*)&Xs[(roff + m) * XPAD + kb];
        bf16x8 b0 = *(const bf16x8*)&Ws[(coff + m) * XPAD + kb];
        bf16x8 b1 = *(const bf16x8*)&Ws[(coff + 16 + m) * XPAD + kb];
        acc0 = __builtin_amdgcn_mfma_f32_16x16x32_bf16(a, b0, acc0, 0, 0, 0);
        acc1 = __builtin_amdgcn_mfma_f32_16x16x32_bf16(a, b1, acc1, 0, 0, 0);
    }
#pragma unroll
    for (int r = 0; r < 4; r++) {
        int row = row0 + roff + q * 4 + r;
        float s = rsqrtf((float)max(cnt_out[row], 1));
        int col0 = cbase + coff + m;
        if constexpr (OUT_FP8) {
            unsigned int pk = __builtin_amdgcn_cvt_pk_fp8_f32(acc0[r] * s, acc1[r] * s, 0, false);
            unsigned char* gp = (unsigned char*)GoutV + (size_t)row * TOTF + col0;
            gp[0]  = (unsigned char)(pk & 0xffu);
            gp[16] = (unsigned char)((pk >> 8) & 0xffu);
        } else {
            unsigned short* Gout = (unsigned short*)GoutV;
            __hip_bfloat16 o0 = __float2bfloat16(acc0[r] * s);
            __hip_bfloat16 o1 = __float2bfloat16(acc1[r] * s);
            Gout[(size_t)row * TOTF + col0]      = *(unsigned short*)&o0;
            Gout[(size_t)row * TOTF + col0 + 16] = *(unsigned short*)&o1;
        }
    }
}

// ================= SpMM column-per-lane helpers (scalar cols, zero cross-lane ops) =================
__device__ __forceinline__ void tail128(const unsigned short* __restrict__ gl, const int* __restrict__ cols,
                                        int b, int d, int j, f32x2& acc) {
    while (j + 16 <= d) {
        unsigned int u[16];
#pragma unroll
        for (int k = 0; k < 16; k++) { int s = cols[b + j + k]; u[k] = gl[(size_t)s * 64]; }
#pragma unroll
        for (int k = 0; k < 16; k++) acc += __builtin_amdgcn_cvt_pk_f32_fp8(u[k], false);
        j += 16;
    }
    if (j + 8 <= d) {
        unsigned int u[8];
#pragma unroll
        for (int k = 0; k < 8; k++) { int s = cols[b + j + k]; u[k] = gl[(size_t)s * 64]; }
#pragma unroll
        for (int k = 0; k < 8; k++) acc += __builtin_amdgcn_cvt_pk_f32_fp8(u[k], false);
        j += 8;
    }
    if (j + 4 <= d) {
        unsigned int u[4];
#pragma unroll
        for (int k = 0; k < 4; k++) { int s = cols[b + j + k]; u[k] = gl[(size_t)s * 64]; }
#pragma unroll
        for (int k = 0; k < 4; k++) acc += __builtin_amdgcn_cvt_pk_f32_fp8(u[k], false);
        j += 4;
    }
    if (j + 2 <= d) {
        unsigned int u0, u1;
        { int s = cols[b + j];     u0 = gl[(size_t)s * 64]; }
        { int s = cols[b + j + 1]; u1 = gl[(size_t)s * 64]; }
        acc += __builtin_amdgcn_cvt_pk_f32_fp8(u0, false);
        acc += __builtin_amdgcn_cvt_pk_f32_fp8(u1, false);
        j += 2;
    }
    if (j < d) {
        int s = cols[b + j];
        unsigned int u = gl[(size_t)s * 64];
        acc += __builtin_amdgcn_cvt_pk_f32_fp8(u, false);
    }
}

__device__ __forceinline__ void tail64(const unsigned char* __restrict__ gl, const int* __restrict__ cols,
                                       int b, int d, int j, f32x2& acc) {
    while (j + 16 <= d) {
        unsigned int u[16];
#pragma unroll
        for (int k = 0; k < 16; k++) { int s = cols[b + j + k]; u[k] = gl[(size_t)s * 64]; }
#pragma unroll
        for (int k = 0; k < 16; k++) acc += __builtin_amdgcn_cvt_pk_f32_fp8(u[k], false);
        j += 16;
    }
    if (j + 8 <= d) {
        unsigned int u[8];
#pragma unroll
        for (int k = 0; k < 8; k++) { int s = cols[b + j + k]; u[k] = gl[(size_t)s * 64]; }
#pragma unroll
        for (int k = 0; k < 8; k++) acc += __builtin_amdgcn_cvt_pk_f32_fp8(u[k], false);
        j += 8;
    }
    if (j + 4 <= d) {
        unsigned int u[4];
#pragma unroll
        for (int k = 0; k < 4; k++) { int s = cols[b + j + k]; u[k] = gl[(size_t)s * 64]; }
#pragma unroll
        for (int k = 0; k < 4; k++) acc += __builtin_amdgcn_cvt_pk_f32_fp8(u[k], false);
        j += 4;
    }
    if (j + 2 <= d) {
        unsigned int u0, u1;
        { int s = cols[b + j];     u0 = gl[(size_t)s * 64]; }
        { int s = cols[b + j + 1]; u1 = gl[(size_t)s * 64]; }
        acc += __builtin_amdgcn_cvt_pk_f32_fp8(u0, false);
        acc += __builtin_amdgcn_cvt_pk_f32_fp8(u1, false);
        j += 2;
    }
    if (j < d) {
        int s = cols[b + j];
        unsigned int u = gl[(size_t)s * 64];
        acc += __builtin_amdgcn_cvt_pk_f32_fp8(u, false);
    }
}

// ================= SpMM F=128 fp8: 2 nodes/wave, merged scalar+gather latency =================
// Lane owns 2 fp8 cols (one ushort). Both nodes' cols s_loads and 8-edge gather batches issue
// before any accumulation -> one exposed latency per pair instead of two.
__global__ __launch_bounds__(256) void k_spmm128f8(const unsigned short* __restrict__ G,
                                                   const int* __restrict__ rp,
                                                   const int* __restrict__ cols,
                                                   const float* __restrict__ bias,
                                                   unsigned int* __restrict__ H) {
    const int lane = threadIdx.x & 63;
    const int wave = threadIdx.x >> 6;
    const int v0 = (blockIdx.x * 4 + wave) * 2;   // grid = N_NODES/8
    const int b0 = __builtin_amdgcn_readfirstlane(rp[v0]);
    const int b1 = __builtin_amdgcn_readfirstlane(rp[v0 + 1]);
    const int e1 = __builtin_amdgcn_readfirstlane(rp[v0 + 2]);
    const int dA = b1 - b0, dB = e1 - b1;
    const unsigned short* gl = G + lane;          // row = 64 ushorts
    f32x2 aA = {0.f, 0.f}, aB = {0.f, 0.f};
    int ja = 0, jb = 0;
    while (ja + 8 <= dA && jb + 8 <= dB) {
        unsigned int u[8], w[8];
#pragma unroll
        for (int k = 0; k < 8; k++) { int s = cols[b0 + ja + k]; u[k] = gl[(size_t)s * 64]; }
#pragma unroll
        for (int k = 0; k < 8; k++) { int s = cols[b1 + jb + k]; w[k] = gl[(size_t)s * 64]; }
#pragma unroll
        for (int k = 0; k < 8; k++) aA += __builtin_amdgcn_cvt_pk_f32_fp8(u[k], false);
#pragma unroll
        for (int k = 0; k < 8; k++) aB += __builtin_amdgcn_cvt_pk_f32_fp8(w[k], false);
        ja += 8; jb += 8;
    }
    tail128(gl, cols, b0, dA, ja, aA);
    tail128(gl, cols, b1, dB, jb, aB);

    {
        const float rs = rsqrtf((float)max(dA, 1));
        const float2 bb = *(const float2*)&bias[2 * lane];
        __hip_bfloat162 p = __float22bfloat162_rn({fmaxf(fmaf(aA.x, rs, bb.x), 0.f),
                                                   fmaxf(fmaf(aA.y, rs, bb.y), 0.f)});
        H[(size_t)v0 * 64 + lane] = *(unsigned int*)&p;
    }
    {
        const float rs = rsqrtf((float)max(dB, 1));
        const float2 bb = *(const float2*)&bias[2 * lane];
        __hip_bfloat162 p = __float22bfloat162_rn({fmaxf(fmaf(aB.x, rs, bb.x), 0.f),
                                                   fmaxf(fmaf(aB.y, rs, bb.y), 0.f)});
        H[(size_t)(v0 + 1) * 64 + lane] = *(unsigned int*)&p;
    }
}

// ================= SpMM F=64 fp8 + FUSED mean-pool: 2 nodes/wave, 8 nodes/block =================
// Lane owns col `lane`. After bias+ReLU, values are staged in LDS acc[8][64]; consecutive rows
// sharing the same (sorted) gid are run-merged and flushed with one global float atomicAdd per
// run per column (~2 runs/block). h2 is never materialized; k_pool is deleted.
__global__ __launch_bounds__(256) void k_spmm64f8(const unsigned char* __restrict__ G,
                                                  const int* __restrict__ rp,
                                                  const int* __restrict__ cols,
                                                  const float* __restrict__ bias,
                                                  const int* __restrict__ gid,
                                                  float* __restrict__ part) {
    __shared__ float acc[8][64];
    __shared__ int gv[8];
    const int lane = threadIdx.x & 63;
    const int wave = threadIdx.x >> 6;
    const int vb = blockIdx.x * 8;                // block owns 8 consecutive nodes
    const int v0 = vb + wave * 2;
    const int b0 = __builtin_amdgcn_readfirstlane(rp[v0]);
    const int b1 = __builtin_amdgcn_readfirstlane(rp[v0 + 1]);
    const int e1 = __builtin_amdgcn_readfirstlane(rp[v0 + 2]);
    const int dA = b1 - b0, dB = e1 - b1;
    const unsigned char* gl = G + lane;           // row = 64 bytes
    if (threadIdx.x < 8) gv[threadIdx.x] = gid[vb + threadIdx.x];
    f32x2 aA = {0.f, 0.f}, aB = {0.f, 0.f};
    int ja = 0, jb = 0;
    while (ja + 8 <= dA && jb + 8 <= dB) {
        unsigned int u[8], w[8];
#pragma unroll
        for (int k = 0; k < 8; k++) { int s = cols[b0 + ja + k]; u[k] = gl[(size_t)s * 64]; }
#pragma unroll
        for (int k = 0; k < 8; k++) { int s = cols[b1 + jb + k]; w[k] = gl[(size_t)s * 64]; }
#pragma unroll
        for (int k = 0; k < 8; k++) aA += __builtin_amdgcn_cvt_pk_f32_fp8(u[k], false);
#pragma unroll
        for (int k = 0; k < 8; k++) aB += __builtin_amdgcn_cvt_pk_f32_fp8(w[k], false);
        ja += 8; jb += 8;
    }
    tail64(gl, cols, b0, dA, ja, aA);
    tail64(gl, cols, b1, dB, jb, aB);

    const float bbias = bias[lane];
    {
        const float rs = rsqrtf((float)max(dA, 1));
        acc[wave * 2][lane] = fmaxf(fmaf(aA.x, rs, bbias), 0.f);
    }
    {
        const float rs = rsqrtf((float)max(dB, 1));
        acc[wave * 2 + 1][lane] = fmaxf(fmaf(aB.x, rs, bbias), 0.f);
    }
    __syncthreads();
    if (threadIdx.x < 64) {
        const int col = threadIdx.x;
        float sum = acc[0][col];
        int g = gv[0];
#pragma unroll
        for (int r = 1; r < 8; r++) {
            int gr = gv[r];
            float v = acc[r][col];
            if (gr != g) {
                atomicAdd(&part[g * 64 + col], sum);
                sum = v;
                g = gr;
            } else {
                sum += v;
            }
        }
        atomicAdd(&part[g * 64 + col], sum);
    }
}

// ---------------- pooling finish + MLP + softmax (block per graph, 64 thr) ----------------
__global__ __launch_bounds__(64) void k_mlp(const float* __restrict__ part,
                                            const int* __restrict__ gid,
                                            const float* __restrict__ fcW1,
                                            const float* __restrict__ fcb1,
                                            const float* __restrict__ fcW2,
                                            const float* __restrict__ fcb2,
                                            float* __restrict__ out) {
    __shared__ int se[2];
    __shared__ float p[64];
    __shared__ float z[10];
    __shared__ float l[10];
    __shared__ float red[2];
    const int g = blockIdx.x;
    const int t = threadIdx.x;  // 64
    if (t < 2) {
        int target = g + t;
        int lo = 0, hi = N_NODES;
        while (lo < hi) {
            int mid = (lo + hi) >> 1;
            if (gid[mid] < target) lo = mid + 1; else hi = mid;
        }
        se[t] = lo;
    }
    __syncthreads();
    const int cnt = max(se[1] - se[0], 1);
    p[t] = part[g * 64 + t] / (float)cnt;
    __syncthreads();
    if (t < 10) {
        float acc = fcb1[t];
        for (int k = 0; k < 64; k++) acc = fmaf(p[k], fcW1[k * 10 + t], acc);
        z[t] = fmaxf(acc, 0.f);
    }
    __syncthreads();
    if (t < 10) {
        float acc = fcb2[t];
        for (int k = 0; k < 10; k++) acc = fmaf(z[k], fcW2[k * 10 + t], acc);
        l[t] = acc;
    }
    __syncthreads();
    if (t == 0) {
        float m = l[0];
        for (int i = 1; i < 10; i++) m = fmaxf(m, l[i]);
        float ssum = 0.f;
        for (int i = 0; i < 10; i++) ssum += expf(l[i] - m);
        red[0] = m;
        red[1] = ssum;
    }
    __syncthreads();
    if (t < 10) out[g * 10 + t] = expf(l[t] - red[0]) / red[1];
}

// ---------------- host ----------------
extern "C" void kernel_launch(void* const* d_in, const int* in_sizes, int n_in,
                              void* d_out, int out_size, void* d_ws, size_t ws_size,
                              hipStream_t stream) {
    const float* feats = (const float*)d_in[0];
    const int* src = (const int*)d_in[1];
    const int* dst = (const int*)d_in[2];
    const int* gid = (const int*)d_in[3];
    const float* W1 = (const float*)d_in[4];
    const float* b1 = (const float*)d_in[5];
    const float* W2 = (const float*)d_in[6];
    const float* b2 = (const float*)d_in[7];
    const float* fcW1 = (const float*)d_in[8];
    const float* fcb1 = (const float*)d_in[9];
    const float* fcW2 = (const float*)d_in[10];
    const float* fcb2 = (const float*)d_in[11];
    float* out = (float*)d_out;

    char* w = (char*)d_ws;
    size_t off = 0;
    auto alloc = [&](size_t bytes) -> void* {
        void* p = w + off;
        off = (off + bytes + 255) & ~(size_t)255;
        return p;
    };
    int* cnt_out = (int*)alloc(N_NODES * 4);
    int* rp      = (int*)alloc((N_NODES + 1) * 4);
    int* cols    = (int*)alloc((size_t)N_EDGES * 4);                         // 6.4 MB tight CSR
    int* Pd      = (int*)alloc(NBUCK * SBLK * 4);                            // 400 KB
    int* Ps      = (int*)alloc(NBUCK * SBLK * 4);
    int* Td      = (int*)alloc(NBUCK * 4);
    int* Ts      = (int*)alloc(NBUCK * 4);
    int* Bd      = (int*)alloc((NBUCK + 1) * 4);
    int* Bs      = (int*)alloc((NBUCK + 1) * 4);
    unsigned int* pb  = (unsigned int*)alloc((size_t)N_EDGES * 4);           // 6.4 MB packed
    unsigned char* sb = (unsigned char*)alloc((size_t)N_EDGES);              // 1.6 MB
    unsigned short* Wt1 = (unsigned short*)alloc(128 * 128 * 2);
    unsigned short* Wt2 = (unsigned short*)alloc(64 * 128 * 2);
    unsigned char* g1 = (unsigned char*)alloc((size_t)N_NODES * 128);        // fp8 e4m3, 12.8 MB
    unsigned short* h1 = (unsigned short*)alloc((size_t)N_NODES * 128 * 2);  // bf16 row-major
    unsigned char* g2 = (unsigned char*)alloc((size_t)N_NODES * 64);         // fp8 e4m3, 6.4 MB
    float* part = (float*)alloc((size_t)N_GRAPHS * 64 * 4);                  // 32 KB pooling accumulator

    // build pipeline (bucket sort both sides; fused absolute tickets in scatter; part zeroed in hist2)
    k_hist2<<<SBLK + NB_PREP, 1024, 0, stream>>>(src, dst, Pd, Ps, W1, W2, Wt1, Wt2, part);
    k_scanA<<<2 * NBUCK, SBLK, 0, stream>>>(Pd, Ps, Td, Ts);
    k_scanB<<<1, 1024, 0, stream>>>(Td, Ts, Bd, Bs);
    k_scatter<<<2 * SBLK, 1024, 0, stream>>>(src, dst, Pd, Ps, Bd, Bs, pb, sb);
    k_finalize<<<NBUCK, 256, 0, stream>>>(pb, Bd, sb, Bs, rp, cnt_out, cols);

    // layer 1 (g1 fp8): single pass over feats, all 128 output cols per block
    k_gemm1<<<N_NODES / 32, 256, 0, stream>>>(feats, Wt1, cnt_out, g1);
    k_spmm128f8<<<N_NODES / 8, 256, 0, stream>>>((const unsigned short*)g1, rp, cols, b1, (unsigned int*)h1);

    // layer 2 (g2 fp8) + fused mean-pool into part
    k_gemm_mfma<64, true, true><<<dim3(N_NODES / 32, 1), 256, 0, stream>>>(h1, Wt2, cnt_out, g2);
    k_spmm64f8<<<N_NODES / 8, 256, 0, stream>>>(g2, rp, cols, b2, gid, part);

    // MLP + softmax (reads pooled accumulator directly)
    k_mlp<<<N_GRAPHS, 64, 0, stream>>>(part, gid, fcW1, fcb1, fcW2, fcb2, out);
}